// Round 8
// baseline (896.101 us; speedup 1.0000x reference)
//
#include <hip/hip_runtime.h>

#define DD 1024
#define FF 4096
#define LL 24
#define VV 50277

typedef float v4f __attribute__((ext_vector_type(4)));

// ---------------- reductions ----------------

__device__ __forceinline__ float wave_sum(float v) {
#pragma unroll
    for (int o = 32; o > 0; o >>= 1) v += __shfl_xor(v, o, 64);
    return v;
}

// single-pass LayerNorm: one block-reduction round for (sum, sumsq)
template <int NW>
__device__ __forceinline__ v4f ln_fast(v4f x, const float* __restrict__ w,
                                       const float* __restrict__ b,
                                       float* scr, int t, bool act) {
    float s1 = act ? (x[0] + x[1] + x[2] + x[3]) : 0.f;
    float s2 = act ? (x[0]*x[0] + x[1]*x[1] + x[2]*x[2] + x[3]*x[3]) : 0.f;
    s1 = wave_sum(s1); s2 = wave_sum(s2);
    int wv = t >> 6;
    __syncthreads();                       // protect scr reuse
    if ((t & 63) == 0) { scr[wv] = s1; scr[NW + wv] = s2; }
    __syncthreads();
    float S1 = 0.f, S2 = 0.f;
#pragma unroll
    for (int i = 0; i < NW; ++i) { S1 += scr[i]; S2 += scr[NW + i]; }
    float m = S1 * (1.0f / 1024.0f);
    float var = S2 * (1.0f / 1024.0f) - m * m;
    float rs = rsqrtf(var + 1e-5f);
    v4f w4 = act ? ((const v4f*)w)[t] : (v4f){0.f, 0.f, 0.f, 0.f};
    v4f b4 = act ? ((const v4f*)b)[t] : (v4f){0.f, 0.f, 0.f, 0.f};
    return (x - m) * rs * w4 + b4;
}

__device__ __forceinline__ v4f mixv(v4f n, v4f s, v4f m) { return n * m + s * (1.0f - m); }

__device__ __forceinline__ float dotv(v4f a, v4f x) {
    return fmaf(a[0], x[0], fmaf(a[1], x[1], fmaf(a[2], x[2], a[3] * x[3])));
}

struct Row { v4f a, b, c, d; };

__device__ __forceinline__ void row_load(Row& r, const float* p, int lane) {
    const v4f* q = (const v4f*)p;
    r.a = q[lane]; r.b = q[lane + 64]; r.c = q[lane + 128]; r.d = q[lane + 192];
}
__device__ __forceinline__ float row_dot(const Row& r, const v4f* v, int lane) {
    return dotv(r.a, v[lane]) + dotv(r.b, v[lane + 64]) +
           dotv(r.c, v[lane + 128]) + dotv(r.d, v[lane + 192]);
}

// ---------------- KA: finish-prev + LN1 + mix + kvr + wkv + ow-partials -----
// 256 blocks x 768 threads (12 waves). Block b owns channels 4b..4b+3.
// wave w (0-11): matrix m=w>>2 (kw/vw/rw), channel 4b+(w&3).

__global__ __launch_bounds__(768, 3) void kA(
    const float* __restrict__ xprev, const float* __restrict__ a1p,
    const float* __restrict__ r2p, const float* __restrict__ sp, float scale_prev,
    const float* __restrict__ enc_w, const float* __restrict__ enc_b,
    const float* __restrict__ st,
    const float* __restrict__ l1w, const float* __restrict__ l1b,
    const float* __restrict__ tmk, const float* __restrict__ tmv,
    const float* __restrict__ tmr, const float* __restrict__ tf,
    const float* __restrict__ td,
    const float* __restrict__ kw, const float* __restrict__ vw,
    const float* __restrict__ rw, const float* __restrict__ ow,
    float* __restrict__ A1i, float* __restrict__ xbuf_i, float* __restrict__ sto) {
    __shared__ __align__(16) v4f s_mix[3][256];
    __shared__ float kvrL[3][4];
    __shared__ __align__(16) float rabL[4];
    __shared__ float scr[24];
    const int t = threadIdx.x, lane = t & 63, w = t >> 6, b = blockIdx.x;

    // hoist independent loads: weight row + ow column chunks
    const int m = w >> 2, ch4 = w & 3;
    Row R;
    row_load(R, (m == 0 ? kw : m == 1 ? vw : rw) + (size_t)(4 * b + ch4) * DD, lane);
    v4f ow0 = *(const v4f*)(ow + (size_t)t * DD + 4 * b);
    v4f ow1;
    if (t < 256) ow1 = *(const v4f*)(ow + (size_t)(768 + t) * DD + 4 * b);

    // finish previous layer (or encoder LN for layer 0)
    v4f xin = {0.f, 0.f, 0.f, 0.f};
    if (t < 256) {
        v4f xp = ((const v4f*)xprev)[t];
        if (enc_w == nullptr) {
            v4f a1 = ((const v4f*)a1p)[t];
            v4f r2 = ((const v4f*)r2p)[t];
            v4f s  = ((const v4f*)sp)[t];
            xin = (xp + a1 + r2 * s) * scale_prev;
        } else xin = xp;
    }
    if (enc_w) xin = ln_fast<12>(xin, enc_w, enc_b, scr, t, t < 256);

    v4f xn = ln_fast<12>(xin, l1w, l1b, scr, t, t < 256);
    if (t < 256) {
        if (b == 0) {
            ((v4f*)(sto + DD))[t] = xn;      // new_st[1] = xn
            ((v4f*)xbuf_i)[t] = xin;         // materialize entry-x of this layer
        }
        v4f sa = ((const v4f*)(st + DD))[t];
        s_mix[0][t] = mixv(xn, sa, ((const v4f*)tmk)[t]);
        s_mix[1][t] = mixv(xn, sa, ((const v4f*)tmv)[t]);
        s_mix[2][t] = mixv(xn, sa, ((const v4f*)tmr)[t]);
    }
    __syncthreads();

    {   // 12 waves: one kvr row each
        float acc = wave_sum(row_dot(R, &s_mix[m][0], lane));
        if (lane == 0) kvrL[m][ch4] = acc;
    }
    __syncthreads();

    if (t < 4) {   // wkv for own 4 channels (no cross-block data needed)
        const int c = 4 * b + t;
        float kk = kvrL[0][t], vv = kvrL[1][t];
        float rr = 1.0f / (1.0f + expf(-kvrL[2][t]));
        float aa = st[2 * DD + c], bb = st[3 * DD + c], pp = st[4 * DD + c];
        float tfv = tf[c], tdv = td[c];
        float ww = tfv + kk;
        float p = fmaxf(pp, ww);
        float e1 = expf(pp - p), e2 = expf(ww - p);
        rabL[t] = rr * ((e1 * aa + e2 * vv) / (e1 * bb + e2));
        float ww2 = pp + tdv;
        float p2 = fmaxf(ww2, kk);
        float f1 = expf(ww2 - p2), f2 = expf(kk - p2);
        sto[2 * DD + c] = f1 * aa + f2 * vv;
        sto[3 * DD + c] = f1 * bb + f2;
        sto[4 * DD + c] = p2;
    }
    __syncthreads();

    {   // ow column partials: A1[j] += ow[j, 4b..4b+3] . rab
        v4f rab4 = *(const v4f*)rabL;
        atomicAdd(&A1i[t], dotv(ow0, rab4));
        if (t < 256) atomicAdd(&A1i[768 + t], dotv(ow1, rab4));
    }
}

// ---------------- KB: x'+LN2+mix + fkw/frw rows + fvw column partials -------
// 256 blocks x 256 threads. Block b owns fkw rows 16b..16b+15 (wave w: 4 rows),
// frw rows 4b..4b+3 (one per wave), fvw columns 16b..16b+15 (one 64B line/j).

__global__ __launch_bounds__(256, 2) void kB(
    const float* __restrict__ xbuf_i, const float* __restrict__ A1i,
    const float* __restrict__ st,
    const float* __restrict__ l2w, const float* __restrict__ l2b,
    const float* __restrict__ ftmk, const float* __restrict__ ftmr,
    const float* __restrict__ fkw, const float* __restrict__ fvw,
    const float* __restrict__ frw,
    float* __restrict__ Si, float* __restrict__ r2o, float* __restrict__ sto) {
    __shared__ __align__(16) v4f s_k[256], s_r[256];
    __shared__ __align__(16) float k2L[16];
    __shared__ float scr[8];
    const int t = threadIdx.x, lane = t & 63, w = t >> 6, b = blockIdx.x;

    const float* fkbase = fkw + (size_t)(16 * b + 4 * w) * DD;
    Row R0;
    row_load(R0, fkbase, lane);      // hoist first row's loads above the LN

    v4f xv = ((const v4f*)xbuf_i)[t] + ((const v4f*)A1i)[t];   // x' = x + ow@rab
    v4f xn2 = ln_fast<4>(xv, l2w, l2b, scr, t, true);
    if (b == 0) ((v4f*)sto)[t] = xn2;                          // new_st[0] = xn2
    {
        v4f sf = ((const v4f*)st)[t];
        s_k[t] = mixv(xn2, sf, ((const v4f*)ftmk)[t]);
        s_r[t] = mixv(xn2, sf, ((const v4f*)ftmr)[t]);
    }
    __syncthreads();

    {   // 4 fkw rows per wave -> k2 = relu^2
        float a0 = wave_sum(row_dot(R0, &s_k[0], lane));
        if (lane == 0) { float rl = fmaxf(a0, 0.f); k2L[4 * w] = rl * rl; }
#pragma unroll
        for (int r = 1; r < 4; ++r) {
            Row R;
            row_load(R, fkbase + (size_t)r * DD, lane);
            float a = wave_sum(row_dot(R, &s_k[0], lane));
            if (lane == 0) { float rl = fmaxf(a, 0.f); k2L[4 * w + r] = rl * rl; }
        }
        // frw row per wave -> r2
        Row Rf;
        row_load(Rf, frw + (size_t)(4 * b + w) * DD, lane);
        float ar = wave_sum(row_dot(Rf, &s_r[0], lane));
        if (lane == 0) r2o[4 * b + w] = 1.0f / (1.0f + expf(-ar));
    }
    __syncthreads();

    {   // fvw column-group partials: S[j] += fvw[j, 16b..16b+15] . k2L
        v4f k0 = ((const v4f*)k2L)[0], k1 = ((const v4f*)k2L)[1];
        v4f k2v = ((const v4f*)k2L)[2], k3 = ((const v4f*)k2L)[3];
#pragma unroll
        for (int jj = 0; jj < 4; ++jj) {
            int j = t + 256 * jj;
            const v4f* q = (const v4f*)(fvw + (size_t)j * FF + 16 * b);
            float part = dotv(q[0], k0) + dotv(q[1], k1) + dotv(q[2], k2v) + dotv(q[3], k3);
            atomicAdd(&Si[j], part);
        }
    }
}

// ---------------- head: finish layer 23 + LN_out + 50277x1024 GEMV ----------

__global__ __launch_bounds__(256) void k_head(
    const float* __restrict__ head_w,
    const float* __restrict__ x23, const float* __restrict__ a1p,
    const float* __restrict__ r2p, const float* __restrict__ sp, float scale,
    const float* __restrict__ olw, const float* __restrict__ olb,
    float* __restrict__ logits) {
    __shared__ __align__(16) v4f xs[256];
    __shared__ float scr[8];
    const int t = threadIdx.x, lane = t & 63, w = t >> 6;
    const int row = blockIdx.x * 4 + w;
    Row W;
    if (row < VV) row_load(W, head_w + (size_t)row * DD, lane);

    v4f xf = (((const v4f*)x23)[t] + ((const v4f*)a1p)[t] +
              ((const v4f*)r2p)[t] * ((const v4f*)sp)[t]) * scale;
    v4f nx = ln_fast<4>(xf, olw, olb, scr, t, true);
    xs[t] = nx;
    __syncthreads();
    if (row < VV) {
        float acc = wave_sum(row_dot(W, &xs[0], lane));
        if (lane == 0) logits[row] = acc;
    }
}

// ---------------- launch ----------------

extern "C" void kernel_launch(void* const* d_in, const int* in_sizes, int n_in,
                              void* d_out, int out_size, void* d_ws, size_t ws_size,
                              hipStream_t stream) {
    const float* token_embd = (const float*)d_in[0];
    const float* state      = (const float*)d_in[1];
    const float* emb_ln_w   = (const float*)d_in[2];
    const float* emb_ln_b   = (const float*)d_in[3];
    const float* ln1_w      = (const float*)d_in[4];
    const float* ln1_b      = (const float*)d_in[5];
    const float* ln2_w      = (const float*)d_in[6];
    const float* ln2_b      = (const float*)d_in[7];
    const float* att_tmk    = (const float*)d_in[8];
    const float* att_tmv    = (const float*)d_in[9];
    const float* att_tmr    = (const float*)d_in[10];
    const float* att_tf     = (const float*)d_in[11];
    const float* att_td     = (const float*)d_in[12];
    const float* att_kw     = (const float*)d_in[13];
    const float* att_vw     = (const float*)d_in[14];
    const float* att_rw     = (const float*)d_in[15];
    const float* att_ow     = (const float*)d_in[16];
    const float* ffn_tmk    = (const float*)d_in[17];
    const float* ffn_tmr    = (const float*)d_in[18];
    const float* ffn_kw     = (const float*)d_in[19];
    const float* ffn_vw     = (const float*)d_in[20];
    const float* ffn_rw     = (const float*)d_in[21];
    const float* out_ln_w   = (const float*)d_in[22];
    const float* out_ln_b   = (const float*)d_in[23];
    const float* head_w     = (const float*)d_in[24];

    float* logits = (float*)d_out;
    float* st_out_base = (float*)d_out + VV;

    float* ws   = (float*)d_ws;
    float* A1   = ws;                    // [24][1024] accumulators (zeroed)
    float* S    = ws + 24 * DD;          // [24][1024] accumulators (zeroed)
    float* r2b  = ws + 48 * DD;          // [24][1024]
    float* xbuf = ws + 72 * DD;          // [24][1024]

    // zero the per-layer accumulators (one async memset, graph-safe)
    hipMemsetAsync(A1, 0, 48 * DD * sizeof(float), stream);

    for (int i = 0; i < LL; ++i) {
        const float* st = state + (size_t)i * 5 * DD;
        float* sto = st_out_base + (size_t)i * 5 * DD;
        const float scale_prev = (i > 0 && i % 6 == 0) ? 0.5f : 1.0f;

        kA<<<256, 768, 0, stream>>>(
            (i == 0) ? token_embd : xbuf + (i - 1) * DD,
            A1 + (i - 1) * DD, r2b + (i - 1) * DD, S + (i - 1) * DD, scale_prev,
            (i == 0) ? emb_ln_w : nullptr, (i == 0) ? emb_ln_b : nullptr,
            st, ln1_w + i * DD, ln1_b + i * DD,
            att_tmk + i * DD, att_tmv + i * DD, att_tmr + i * DD,
            att_tf + i * DD, att_td + i * DD,
            att_kw + (size_t)i * DD * DD, att_vw + (size_t)i * DD * DD,
            att_rw + (size_t)i * DD * DD, att_ow + (size_t)i * DD * DD,
            A1 + i * DD, xbuf + i * DD, sto);

        kB<<<256, 256, 0, stream>>>(
            xbuf + i * DD, A1 + i * DD, st,
            ln2_w + i * DD, ln2_b + i * DD,
            ffn_tmk + i * DD, ffn_tmr + i * DD,
            ffn_kw + (size_t)i * FF * DD, ffn_vw + (size_t)i * DD * FF,
            ffn_rw + (size_t)i * DD * DD,
            S + i * DD, r2b + i * DD, sto);
    }

    // layer-23 finish (scale = 0.5 since 24 % 6 == 0) folded into head
    k_head<<<(VV + 3) / 4, 256, 0, stream>>>(
        head_w, xbuf + 23 * DD, A1 + 23 * DD, r2b + 23 * DD, S + 23 * DD, 0.5f,
        out_ln_w, out_ln_b, logits);
}

// Round 9
// 595.821 us; speedup vs baseline: 1.5040x; 1.5040x over previous
//
#include <hip/hip_runtime.h>

#define DD 1024
#define FF 4096
#define LL 24
#define VV 50277

typedef float v4f __attribute__((ext_vector_type(4)));

// ---------------- reductions ----------------

__device__ __forceinline__ float wave_sum(float v) {
#pragma unroll
    for (int o = 32; o > 0; o >>= 1) v += __shfl_xor(v, o, 64);
    return v;
}

// single-pass LayerNorm over D=1024, 256-thread block: one reduction round
__device__ __forceinline__ v4f ln_fast(v4f x, const float* __restrict__ w,
                                       const float* __restrict__ b,
                                       float* scr, int t) {
    float s1 = x[0] + x[1] + x[2] + x[3];
    float s2 = x[0]*x[0] + x[1]*x[1] + x[2]*x[2] + x[3]*x[3];
    s1 = wave_sum(s1); s2 = wave_sum(s2);
    int wv = t >> 6;
    __syncthreads();                       // protect scr reuse across calls
    if ((t & 63) == 0) { scr[wv] = s1; scr[4 + wv] = s2; }
    __syncthreads();
    float S1 = scr[0] + scr[1] + scr[2] + scr[3];
    float S2 = scr[4] + scr[5] + scr[6] + scr[7];
    float m = S1 * (1.0f / 1024.0f);
    float var = S2 * (1.0f / 1024.0f) - m * m;
    float rs = rsqrtf(var + 1e-5f);
    v4f w4 = ((const v4f*)w)[t], b4 = ((const v4f*)b)[t];
    return (x - m) * rs * w4 + b4;
}

__device__ __forceinline__ v4f mixv(v4f n, v4f s, v4f m) { return n * m + s * (1.0f - m); }

__device__ __forceinline__ float dotv(v4f a, v4f x) {
    return fmaf(a[0], x[0], fmaf(a[1], x[1], fmaf(a[2], x[2], a[3] * x[3])));
}

struct Row { v4f a, b, c, d; };

__device__ __forceinline__ void row_load(Row& r, const float* p, int lane) {
    const v4f* q = (const v4f*)p;
    r.a = q[lane]; r.b = q[lane + 64]; r.c = q[lane + 128]; r.d = q[lane + 192];
}
__device__ __forceinline__ void row_pin(Row& r) {   // force loads issued here
    asm volatile("" : "+v"(r.a), "+v"(r.b), "+v"(r.c), "+v"(r.d));
}
__device__ __forceinline__ float row_dot(const Row& r, const v4f* v, int lane) {
    return dotv(r.a, v[lane]) + dotv(r.b, v[lane + 64]) +
           dotv(r.c, v[lane + 128]) + dotv(r.d, v[lane + 192]);
}

// ---------------- K1: [enc LN +] LN1 + time-mix + {kw,vw,rw} GEMV ----------
// grid = 768 blocks; wave w of block b owns combined row 4b+w of [kw;vw;rw].

__global__ __launch_bounds__(256) void k1_timemix(
    const float* __restrict__ xin, const float* __restrict__ st,
    const float* __restrict__ enc_w, const float* __restrict__ enc_b,
    const float* __restrict__ l1w, const float* __restrict__ l1b,
    const float* __restrict__ tmk, const float* __restrict__ tmv,
    const float* __restrict__ tmr,
    const float* __restrict__ kw, const float* __restrict__ vw,
    const float* __restrict__ rw,
    float* __restrict__ kk, float* __restrict__ vv, float* __restrict__ rr,
    float* __restrict__ x0out, float* __restrict__ st_out) {
    __shared__ __align__(16) v4f s_k[256], s_v[256], s_r[256];
    __shared__ float scr[8];
    const int t = threadIdx.x, lane = t & 63, w = t >> 6, b = blockIdx.x;

    // hoist weight row: streaming starts at t=0, overlaps LN/mix below
    const int ridx = 4 * b + w, m = ridx >> 10, row = ridx & 1023;
    Row W;
    row_load(W, (m == 0 ? kw : m == 1 ? vw : rw) + (size_t)row * DD, lane);
    row_pin(W);

    v4f xv = ((const v4f*)xin)[t];
    if (enc_w) xv = ln_fast(xv, enc_w, enc_b, scr, t);   // x0 = LN(token_embd)
    if (x0out && b == 0) ((v4f*)x0out)[t] = xv;          // publish x0
    v4f n = ln_fast(xv, l1w, l1b, scr, t);
    if (b == 0) ((v4f*)(st_out + DD))[t] = n;            // new_st[1] = xn
    {
        v4f sa = ((const v4f*)(st + DD))[t];
        s_k[t] = mixv(n, sa, ((const v4f*)tmk)[t]);
        s_v[t] = mixv(n, sa, ((const v4f*)tmv)[t]);
        s_r[t] = mixv(n, sa, ((const v4f*)tmr)[t]);
    }
    __syncthreads();

    const v4f* vec = (m == 0) ? s_k : (m == 1) ? s_v : s_r;
    float acc = wave_sum(row_dot(W, vec, lane));
    if (lane == 0) {
        if (m == 0)      kk[row] = acc;
        else if (m == 1) vv[row] = acc;
        else             rr[row] = 1.0f / (1.0f + expf(-acc));
    }
}

// ---------------- K2: wkv elementwise + state write + ow GEMV + residual ----
// grid = 256 blocks

__global__ __launch_bounds__(256) void k2_wkv_out(
    const float* __restrict__ st, const float* __restrict__ tf,
    const float* __restrict__ td,
    const float* __restrict__ kk, const float* __restrict__ vv,
    const float* __restrict__ rr, const float* __restrict__ ow,
    float* __restrict__ x, float* __restrict__ st_out) {
    __shared__ __align__(16) v4f rab[256];
    const int t = threadIdx.x, lane = t & 63, w = t >> 6, b = blockIdx.x;

    // hoist ow row
    const int row = 4 * b + w;
    Row W;
    row_load(W, ow + (size_t)row * DD, lane);
    row_pin(W);

    {
        v4f kx = ((const v4f*)kk)[t];
        v4f vx = ((const v4f*)vv)[t];
        v4f rx = ((const v4f*)rr)[t];
        v4f aa = ((const v4f*)(st + 2 * DD))[t];
        v4f bb = ((const v4f*)(st + 3 * DD))[t];
        v4f pp = ((const v4f*)(st + 4 * DD))[t];
        v4f tf4 = ((const v4f*)tf)[t];
        v4f td4 = ((const v4f*)td)[t];
        v4f rb, naa, nbb, np2;
#pragma unroll
        for (int c = 0; c < 4; ++c) {
            float kc = kx[c], vc = vx[c];
            float wwc = tf4[c] + kc;
            float p = fmaxf(pp[c], wwc);
            float e1 = expf(pp[c] - p), e2 = expf(wwc - p);
            rb[c] = rx[c] * ((e1 * aa[c] + e2 * vc) / (e1 * bb[c] + e2));
            float ww2 = pp[c] + td4[c];
            float p2 = fmaxf(ww2, kc);
            float f1 = expf(ww2 - p2), f2 = expf(kc - p2);
            naa[c] = f1 * aa[c] + f2 * vc;
            nbb[c] = f1 * bb[c] + f2;
            np2[c] = p2;
        }
        rab[t] = rb;
        if (b == 0) {
            ((v4f*)(st_out + 2 * DD))[t] = naa;
            ((v4f*)(st_out + 3 * DD))[t] = nbb;
            ((v4f*)(st_out + 4 * DD))[t] = np2;
        }
    }
    __syncthreads();

    float acc = wave_sum(row_dot(W, &rab[0], lane));
    if (lane == 0) x[row] += acc;    // residual
}

// ---------------- K3: LN2 + chan-mix + {fkw,frw} GEMV (relu^2 / sigmoid) ----
// grid = 1280 blocks (5120 combined rows)

__global__ __launch_bounds__(256) void k3_ffn_kr(
    const float* __restrict__ x, const float* __restrict__ st,
    const float* __restrict__ l2w, const float* __restrict__ l2b,
    const float* __restrict__ ftmk, const float* __restrict__ ftmr,
    const float* __restrict__ fkw, const float* __restrict__ frw,
    float* __restrict__ k2, float* __restrict__ r2, float* __restrict__ st_out) {
    __shared__ __align__(16) v4f s_k[256], s_r[256];
    __shared__ float scr[8];
    const int t = threadIdx.x, lane = t & 63, w = t >> 6, b = blockIdx.x;

    // hoist weight row
    const int ridx = 4 * b + w;
    Row W;
    row_load(W, (ridx < FF ? fkw + (size_t)ridx * DD
                           : frw + (size_t)(ridx - FF) * DD), lane);
    row_pin(W);

    v4f xv = ((const v4f*)x)[t];
    v4f n = ln_fast(xv, l2w, l2b, scr, t);
    if (b == 0) ((v4f*)st_out)[t] = n;                   // new_st[0] = xn2
    {
        v4f sf = ((const v4f*)st)[t];
        s_k[t] = mixv(n, sf, ((const v4f*)ftmk)[t]);
        s_r[t] = mixv(n, sf, ((const v4f*)ftmr)[t]);
    }
    __syncthreads();

    const v4f* vec = (ridx < FF) ? s_k : s_r;
    float acc = wave_sum(row_dot(W, vec, lane));
    if (lane == 0) {
        if (ridx < FF) { float rl = fmaxf(acc, 0.f); k2[ridx] = rl * rl; }
        else           r2[ridx - FF] = 1.0f / (1.0f + expf(-acc));
    }
}

// ---------------- K4: fvw GEMV + gated residual + rescale -------------------
// grid = 256 blocks; wave w owns row 4b+w (4096-wide dot)

__global__ __launch_bounds__(256) void k4_ffn_v(
    const float* __restrict__ fvw, const float* __restrict__ k2,
    const float* __restrict__ r2, float* __restrict__ x, float scale) {
    __shared__ __align__(16) v4f k2s[1024];
    const int t = threadIdx.x, lane = t & 63, w = t >> 6, b = blockIdx.x;
    const int row = 4 * b + w;
    const v4f* W4 = (const v4f*)(fvw + (size_t)row * FF);

    // hoist first half of the row (8 x v4f = 32 VGPRs), pinned at t=0
    v4f h0 = W4[lane],       h1 = W4[lane + 64],  h2 = W4[lane + 128], h3 = W4[lane + 192];
    v4f h4 = W4[lane + 256], h5 = W4[lane + 320], h6 = W4[lane + 384], h7 = W4[lane + 448];
    asm volatile("" : "+v"(h0), "+v"(h1), "+v"(h2), "+v"(h3),
                      "+v"(h4), "+v"(h5), "+v"(h6), "+v"(h7));

    // stage k2 vector to LDS
#pragma unroll
    for (int j = 0; j < 4; ++j)
        k2s[t + 256 * j] = ((const v4f*)k2)[t + 256 * j];
    __syncthreads();

    float acc = dotv(h0, k2s[lane])       + dotv(h1, k2s[lane + 64]) +
                dotv(h2, k2s[lane + 128]) + dotv(h3, k2s[lane + 192]) +
                dotv(h4, k2s[lane + 256]) + dotv(h5, k2s[lane + 320]) +
                dotv(h6, k2s[lane + 384]) + dotv(h7, k2s[lane + 448]);
#pragma unroll
    for (int j = 8; j < 16; ++j) {
        v4f a = W4[lane + 64 * j];
        acc += dotv(a, k2s[lane + 64 * j]);
    }
    acc = wave_sum(acc);
    if (lane == 0) x[row] = (x[row] + r2[row] * acc) * scale;
}

// ---------------- head: folded final LN + 50277x1024 GEMV -------------------

__global__ __launch_bounds__(256) void k_head(const float* __restrict__ head_w,
                                              const float* __restrict__ x,
                                              const float* __restrict__ olw,
                                              const float* __restrict__ olb,
                                              float* __restrict__ logits) {
    __shared__ __align__(16) v4f xs[256];
    __shared__ float scr[8];
    const int t = threadIdx.x, lane = t & 63, w = t >> 6;
    const int row = blockIdx.x * 4 + w;
    Row W;
    if (row < VV) { row_load(W, head_w + (size_t)row * DD, lane); row_pin(W); }

    v4f xv = ((const v4f*)x)[t];
    v4f nx = ln_fast(xv, olw, olb, scr, t);
    xs[t] = nx;
    __syncthreads();
    if (row < VV) {
        float acc = wave_sum(row_dot(W, &xs[0], lane));
        if (lane == 0) logits[row] = acc;
    }
}

// ---------------- launch ----------------

extern "C" void kernel_launch(void* const* d_in, const int* in_sizes, int n_in,
                              void* d_out, int out_size, void* d_ws, size_t ws_size,
                              hipStream_t stream) {
    const float* token_embd = (const float*)d_in[0];
    const float* state      = (const float*)d_in[1];
    const float* emb_ln_w   = (const float*)d_in[2];
    const float* emb_ln_b   = (const float*)d_in[3];
    const float* ln1_w      = (const float*)d_in[4];
    const float* ln1_b      = (const float*)d_in[5];
    const float* ln2_w      = (const float*)d_in[6];
    const float* ln2_b      = (const float*)d_in[7];
    const float* att_tmk    = (const float*)d_in[8];
    const float* att_tmv    = (const float*)d_in[9];
    const float* att_tmr    = (const float*)d_in[10];
    const float* att_tf     = (const float*)d_in[11];
    const float* att_td     = (const float*)d_in[12];
    const float* att_kw     = (const float*)d_in[13];
    const float* att_vw     = (const float*)d_in[14];
    const float* att_rw     = (const float*)d_in[15];
    const float* att_ow     = (const float*)d_in[16];
    const float* ffn_tmk    = (const float*)d_in[17];
    const float* ffn_tmr    = (const float*)d_in[18];
    const float* ffn_kw     = (const float*)d_in[19];
    const float* ffn_vw     = (const float*)d_in[20];
    const float* ffn_rw     = (const float*)d_in[21];
    const float* out_ln_w   = (const float*)d_in[22];
    const float* out_ln_b   = (const float*)d_in[23];
    const float* head_w     = (const float*)d_in[24];

    float* logits = (float*)d_out;
    float* st_out_base = (float*)d_out + VV;

    float* ws  = (float*)d_ws;
    float* x   = ws;             // 1024
    float* kk  = ws + 1024;
    float* vv  = ws + 2048;
    float* rr  = ws + 3072;
    float* k2b = ws + 4096;      // 4096
    float* r2b = ws + 8192;      // 1024

    for (int i = 0; i < LL; ++i) {
        const float* st = state + (size_t)i * 5 * DD;
        float* sto = st_out_base + (size_t)i * 5 * DD;

        k1_timemix<<<768, 256, 0, stream>>>(
            (i == 0) ? token_embd : x, st,
            (i == 0) ? emb_ln_w : nullptr, (i == 0) ? emb_ln_b : nullptr,
            ln1_w + i * DD, ln1_b + i * DD,
            att_tmk + i * DD, att_tmv + i * DD, att_tmr + i * DD,
            att_kw + (size_t)i * DD * DD, att_vw + (size_t)i * DD * DD,
            att_rw + (size_t)i * DD * DD,
            kk, vv, rr, (i == 0) ? x : nullptr, sto);

        k2_wkv_out<<<256, 256, 0, stream>>>(
            st, att_tf + i * DD, att_td + i * DD, kk, vv, rr,
            att_ow + (size_t)i * DD * DD, x, sto);

        k3_ffn_kr<<<1280, 256, 0, stream>>>(
            x, st, ln2_w + i * DD, ln2_b + i * DD,
            ffn_tmk + i * DD, ffn_tmr + i * DD,
            ffn_kw + (size_t)i * FF * DD, ffn_rw + (size_t)i * DD * DD,
            k2b, r2b, sto);

        float scale = ((i + 1) % 6 == 0) ? 0.5f : 1.0f;
        k4_ffn_v<<<256, 256, 0, stream>>>(
            ffn_vw + (size_t)i * DD * FF, k2b, r2b, x, scale);
    }

    k_head<<<(VV + 3) / 4, 256, 0, stream>>>(head_w, x, out_ln_w, out_ln_b, logits);
}